// Round 9
// baseline (443.581 us; speedup 1.0000x reference)
//
#include <hip/hip_runtime.h>
#include <math.h>

#define NN 50000
#define NE 800000
#define TM 16
#define NB 782          // node blocks per panel (64 nodes/block)

typedef _Float16 half4v __attribute__((ext_vector_type(4)));
typedef _Float16 half8v __attribute__((ext_vector_type(8)));
typedef float f32x4 __attribute__((ext_vector_type(4)));

__device__ __forceinline__ float relu(float v) { return fmaxf(v, 0.0f); }

// ---- degree count over dst ----
__global__ __launch_bounds__(256) void k_deg(const int* __restrict__ ei,
                                             int* __restrict__ deg) {
  int e = blockIdx.x * 256 + threadIdx.x;
  if (e < NE) atomicAdd(&deg[ei[NE + e]], 1);
}

// ---- d^-1/2 ----
__global__ __launch_bounds__(256) void k_dinv(const int* __restrict__ deg,
                                              float* __restrict__ dinv) {
  int i = blockIdx.x * 256 + threadIdx.x;
  if (i < NN) {
    int d = deg[i];
    dinv[i] = d > 0 ? 1.0f / sqrtf((float)d) : 0.0f;
  }
}

// ---- exclusive scan of deg -> rowptr (single 1024-thread block) ----
__global__ __launch_bounds__(1024) void k_scan(const int* __restrict__ deg,
                                               int* __restrict__ rowptr) {
  __shared__ int swave[16];
  __shared__ int scarry;
  const int tid = threadIdx.x;
  const int lane = tid & 63;
  const int wid = tid >> 6;
  if (tid == 0) scarry = 0;
  __syncthreads();
  for (int base = 0; base < NN; base += 1024) {
    int i = base + tid;
    int v = (i < NN) ? deg[i] : 0;
    int sum = v;
#pragma unroll
    for (int off = 1; off < 64; off <<= 1) {
      int t = __shfl_up(sum, off);
      if (lane >= off) sum += t;
    }
    if (lane == 63) swave[wid] = sum;
    __syncthreads();
    int wbase = 0;
    for (int w = 0; w < wid; ++w) wbase += swave[w];
    int carry = scarry;
    if (i < NN) rowptr[i] = carry + wbase + sum - v;
    __syncthreads();
    if (tid == 1023) scarry = carry + wbase + sum;
    __syncthreads();
  }
  if (tid == 0) rowptr[NN] = scarry;
}

// ---- CSR fill + edge weights ----
__global__ __launch_bounds__(256) void k_fill(const int* __restrict__ ei,
                                              const float* __restrict__ dinv,
                                              const int* __restrict__ rowptr,
                                              int* __restrict__ fill,
                                              int* __restrict__ col,
                                              float* __restrict__ wgt) {
  int e = blockIdx.x * 256 + threadIdx.x;
  if (e < NE) {
    int s = ei[e];
    int d = ei[NE + e];
    float w = dinv[s] * dinv[d] * 0.5f;
    int pos = rowptr[d] + atomicAdd(&fill[d], 1);
    col[pos] = s;
    wgt[pos] = w;
  }
}

// ---- x (f32 [N][128]) -> panel f16 [4][N][32] ----
__global__ __launch_bounds__(256) void k_x2p(const float* __restrict__ x,
                                             _Float16* __restrict__ xp) {
  int i = blockIdx.x * 256 + threadIdx.x;  // over NN*16 16B-chunks
  if (i >= NN * 16) return;
  int n = i >> 4;
  int sub = i & 15;
  int p = sub >> 2, l = sub & 3;
  const float* src = x + (size_t)n * 128 + p * 32 + l * 8;
  float4 v0 = *(const float4*)src;
  float4 v1 = *(const float4*)(src + 4);
  half8v h;
  h[0] = (_Float16)v0.x; h[1] = (_Float16)v0.y;
  h[2] = (_Float16)v0.z; h[3] = (_Float16)v0.w;
  h[4] = (_Float16)v1.x; h[5] = (_Float16)v1.y;
  h[6] = (_Float16)v1.z; h[7] = (_Float16)v1.w;
  *(half8v*)(xp + (size_t)p * NN * 32 + (size_t)n * 32 + l * 8) = h;
}

// ---- one hop, panel-major: per panel p the working set is 3.2 MB (L2-fit).
// grid = 4*NB; panel = bid/NB. 4 lanes/node x 16B, 64 nodes/block.
__global__ __launch_bounds__(256) void k_hop_p(const _Float16* __restrict__ in,
                                               _Float16* __restrict__ out,
                                               const int* __restrict__ rowptr,
                                               const int* __restrict__ col,
                                               const float* __restrict__ wgt) {
  const int bid = blockIdx.x;
  const int p = bid / NB;
  const int nb = bid - p * NB;
  const int t = threadIdx.x;
  const int node = nb * 64 + (t >> 2);
  const int lane = t & 3;
  if (node >= NN) return;
  const half8v* in8 = (const half8v*)(in + (size_t)p * NN * 32);
  half8v a = in8[(size_t)node * 4 + lane];
  float acc[8];
#pragma unroll
  for (int j = 0; j < 8; ++j) acc[j] = 0.5f * (float)a[j];
  int e = rowptr[node], e1 = rowptr[node + 1];
  for (; e + 4 <= e1; e += 4) {
    int c0 = col[e], c1 = col[e + 1], c2 = col[e + 2], c3 = col[e + 3];
    float w0 = wgt[e], w1 = wgt[e + 1], w2 = wgt[e + 2], w3 = wgt[e + 3];
    half8v v0 = in8[(size_t)c0 * 4 + lane];
    half8v v1 = in8[(size_t)c1 * 4 + lane];
    half8v v2 = in8[(size_t)c2 * 4 + lane];
    half8v v3 = in8[(size_t)c3 * 4 + lane];
#pragma unroll
    for (int j = 0; j < 8; ++j)
      acc[j] += w0 * (float)v0[j] + w1 * (float)v1[j] +
                w2 * (float)v2[j] + w3 * (float)v3[j];
  }
  for (; e < e1; ++e) {
    float w = wgt[e];
    half8v v = in8[(size_t)col[e] * 4 + lane];
#pragma unroll
    for (int j = 0; j < 8; ++j) acc[j] += w * (float)v[j];
  }
  half8v r;
#pragma unroll
  for (int j = 0; j < 8; ++j) r[j] = (_Float16)acc[j];
  ((half8v*)(out + (size_t)p * NN * 32))[(size_t)node * 4 + lane] = r;
}

// ---- prep: weights -> f16 fragment-order [m][ct(8)][ks(4)][lane(64)][8] ----
__global__ __launch_bounds__(256) void k_prep(const float* __restrict__ W_low,
                                              const float* __restrict__ W_band,
                                              const float* __restrict__ W_mlp,
                                              _Float16* __restrict__ WTs) {
  int m = blockIdx.x;  // 0..6 channels, 7..8 mlp chunks
  const float* src;
  if (m < 4)      src = W_low + m * 16384;
  else if (m < 7) src = W_band + (m - 4) * 16384;
  else            src = W_mlp + (m - 7) * 16384;
  _Float16* dst = WTs + (size_t)m * 16384;
  for (int s = threadIdx.x; s < 2048; s += 256) {
    int ct = s >> 8;          // col tile 0..7
    int ks = (s >> 6) & 3;    // k step 0..3
    int lane = s & 63;
    int mcol = lane & 15, kg = lane >> 4;
    int colc = ct * 16 + mcol;
    int k0 = ks * 32 + 4 * kg;
    _Float16* d = dst + (size_t)s * 8;
#pragma unroll
    for (int j = 0; j < 4; ++j) d[j] = (_Float16)src[(k0 + j) * 128 + colc];
#pragma unroll
    for (int j = 0; j < 4; ++j) d[4 + j] = (_Float16)src[(k0 + 16 + j) * 128 + colc];
  }
}

// A-fragment load from panel layout: panel ks, node row node0+mrow
#define LOADP(dst, src)                                                        \
  {                                                                            \
    _Pragma("unroll")                                                          \
    for (int ks = 0; ks < 4; ++ks) {                                           \
      const _Float16* p_ =                                                     \
          (src) + (size_t)ks * NN * 32 + (size_t)(node0 + mrow) * 32;          \
      half4v lo_ = *(const half4v*)&p_[4 * kg];                                \
      half4v hi_ = *(const half4v*)&p_[4 * kg + 16];                           \
      dst[ks] = __builtin_shufflevector(lo_, hi_, 0, 1, 2, 3, 4, 5, 6, 7);     \
    }                                                                          \
  }

// One channel GEMM: f32 accumulate, bias added, packed to f16 registers
#define CH_GEMM(c, AEXPR, BIASPTR)                                             \
  {                                                                            \
    const _Float16* wc_ = WTs + (size_t)(c) * 16384;                           \
    f32x4 A0_ = {0.f, 0.f, 0.f, 0.f}, A1_ = {0.f, 0.f, 0.f, 0.f};              \
    _Pragma("unroll")                                                          \
    for (int ks = 0; ks < 4; ++ks) {                                           \
      half8v af_ = (AEXPR);                                                    \
      half8v bf0_ = *(const half8v*)&wc_[(size_t)(2 * wid) * 2048 + ks * 512 + lane * 8];     \
      half8v bf1_ = *(const half8v*)&wc_[(size_t)(2 * wid + 1) * 2048 + ks * 512 + lane * 8]; \
      A0_ = __builtin_amdgcn_mfma_f32_16x16x32_f16(af_, bf0_, A0_, 0, 0, 0);   \
      A1_ = __builtin_amdgcn_mfma_f32_16x16x32_f16(af_, bf1_, A1_, 0, 0, 0);   \
    }                                                                          \
    float bv0_ = (BIASPTR)[colw + mrow], bv1_ = (BIASPTR)[colw + 16 + mrow];   \
    half4v H0_, H1_;                                                           \
    _Pragma("unroll")                                                          \
    for (int r = 0; r < 4; ++r) {                                              \
      H0_[r] = (_Float16)(A0_[r] + bv0_);                                      \
      H1_[r] = (_Float16)(A1_[r] + bv1_);                                      \
    }                                                                          \
    h0[c] = H0_; h1[c] = H1_;                                                  \
  }

// ---- fused MFMA: 7-channel GEMM (h in f16 registers) + attention + MLP ----
__global__ __launch_bounds__(256) void k_fused(
    const _Float16* __restrict__ xh, const _Float16* __restrict__ a1,
    const _Float16* __restrict__ a2, const _Float16* __restrict__ a4,
    const _Float16* __restrict__ WTs,
    const float* __restrict__ b_low, const float* __restrict__ b_band,
    const float* __restrict__ apre_l, const float* __restrict__ ach_l,
    const float* __restrict__ apre_b, const float* __restrict__ ach_b,
    const float* __restrict__ b_mlp, float* __restrict__ out) {
  __shared__ float pD[2][TM][4];     // [low|band][node][wave] pre-dot partials
  __shared__ float pS[7][TM][4];     // [chan][node][wave] chan-dot partials
  __shared__ float aB[TM][8];        // alpha per node (7 used)
  __shared__ _Float16 sV[TM][264];   // MLP input [node][256]+pad

  const int tid = threadIdx.x;
  const int wid = tid >> 6;
  const int lane = tid & 63;
  const int mrow = lane & 15;
  const int kg = lane >> 4;
  const int node0 = blockIdx.x * TM;
  const int colw = wid * 32;

  half4v h0[7], h1[7];  // per-channel outputs (bias included), f16-packed

  // ---- all 32 A-fragment loads issued upfront (one latency exposure) ----
  half8v fX[4], f1[4], f2[4], f4[4];
  LOADP(fX, xh);
  LOADP(f1, a1);
  LOADP(f2, a2);
  LOADP(f4, a4);

  CH_GEMM(0, fX[ks], b_low + 0 * 128);
  CH_GEMM(4, fX[ks] - f1[ks], b_band + 0 * 128);
  CH_GEMM(1, f1[ks], b_low + 1 * 128);
  CH_GEMM(5, f1[ks] - f2[ks], b_band + 1 * 128);
  CH_GEMM(2, f2[ks], b_low + 2 * 128);
  CH_GEMM(6, f2[ks] - f4[ks], b_band + 2 * 128);
  CH_GEMM(3, f4[ks], b_low + 3 * 128);

  // ---- attention partials in-register ----
  const float apl0 = apre_l[colw + mrow], apl1 = apre_l[colw + 16 + mrow];
  const float acl0 = ach_l[colw + mrow],  acl1 = ach_l[colw + 16 + mrow];
  const float apb0 = apre_b[colw + mrow], apb1 = apre_b[colw + 16 + mrow];
  const float acb0 = ach_b[colw + mrow],  acb1 = ach_b[colw + 16 + mrow];

  float dpl[4] = {0.f, 0.f, 0.f, 0.f}, dpb[4] = {0.f, 0.f, 0.f, 0.f};
  float sc[7][4];
#pragma unroll
  for (int c = 0; c < 7; ++c) {
#pragma unroll
    for (int r = 0; r < 4; ++r) {
      float r0 = relu((float)h0[c][r]);
      float r1 = relu((float)h1[c][r]);
      if (c < 4) {
        dpl[r] += r0 * apl0 + r1 * apl1;
        sc[c][r] = r0 * acl0 + r1 * acl1;
      } else {
        dpb[r] += r0 * apb0 + r1 * apb1;
        sc[c][r] = r0 * acb0 + r1 * acb1;
      }
    }
  }
#pragma unroll
  for (int r = 0; r < 4; ++r) { dpl[r] *= 0.25f; dpb[r] *= (1.0f / 3.0f); }
  // reduce over the 16 mrow lanes (lane bits 0..3)
#pragma unroll
  for (int m = 1; m <= 8; m <<= 1) {
#pragma unroll
    for (int r = 0; r < 4; ++r) {
      dpl[r] += __shfl_xor(dpl[r], m);
      dpb[r] += __shfl_xor(dpb[r], m);
    }
#pragma unroll
    for (int c = 0; c < 7; ++c)
#pragma unroll
      for (int r = 0; r < 4; ++r) sc[c][r] += __shfl_xor(sc[c][r], m);
  }
  if (mrow == 0) {
#pragma unroll
    for (int r = 0; r < 4; ++r) {
      pD[0][4 * kg + r][wid] = dpl[r];
      pD[1][4 * kg + r][wid] = dpb[r];
#pragma unroll
      for (int c = 0; c < 7; ++c) pS[c][4 * kg + r][wid] = sc[c][r];
    }
  }
  __syncthreads();

  // ---- softmax over channels (one thread per node) ----
  if (tid < TM) {
    const int n = tid;
    float dl = pD[0][n][0] + pD[0][n][1] + pD[0][n][2] + pD[0][n][3];
    float db = pD[1][n][0] + pD[1][n][1] + pD[1][n][2] + pD[1][n][3];
    float lg[7];
#pragma unroll
    for (int c = 0; c < 7; ++c) {
      float s = pS[c][n][0] + pS[c][n][1] + pS[c][n][2] + pS[c][n][3];
      lg[c] = relu((c < 4 ? dl : db) + s);
    }
    float ml = fmaxf(fmaxf(lg[0], lg[1]), fmaxf(lg[2], lg[3]));
    float e0 = expf(lg[0] - ml), e1 = expf(lg[1] - ml);
    float e2 = expf(lg[2] - ml), e3 = expf(lg[3] - ml);
    float invl = 1.0f / (e0 + e1 + e2 + e3);
    float mb = fmaxf(fmaxf(lg[4], lg[5]), lg[6]);
    float f4e = expf(lg[4] - mb), f5e = expf(lg[5] - mb), f6e = expf(lg[6] - mb);
    float invb = 1.0f / (f4e + f5e + f6e);
    aB[n][0] = e0 * invl; aB[n][1] = e1 * invl;
    aB[n][2] = e2 * invl; aB[n][3] = e3 * invl;
    aB[n][4] = f4e * invb; aB[n][5] = f5e * invb; aB[n][6] = f6e * invb;
  }
  __syncthreads();

  // ---- weighted sum straight from registers -> sV ----
#pragma unroll
  for (int r = 0; r < 4; ++r) {
    const int n = 4 * kg + r;
    float vl0 = 0.f, vl1 = 0.f, vb0 = 0.f, vb1 = 0.f;
#pragma unroll
    for (int c = 0; c < 4; ++c) {
      float a = aB[n][c];
      vl0 += a * (float)h0[c][r];
      vl1 += a * (float)h1[c][r];
    }
#pragma unroll
    for (int c = 4; c < 7; ++c) {
      float a = aB[n][c];
      vb0 += a * (float)h0[c][r];
      vb1 += a * (float)h1[c][r];
    }
    sV[n][colw + mrow] = (_Float16)vl0;
    sV[n][colw + 16 + mrow] = (_Float16)vl1;
    sV[n][128 + colw + mrow] = (_Float16)vb0;
    sV[n][128 + colw + 16 + mrow] = (_Float16)vb1;
  }
  __syncthreads();

  // ---- MLP: [TM,256] @ [256,128], coalesced B frags ----
  f32x4 m0 = {0.f, 0.f, 0.f, 0.f}, m1 = {0.f, 0.f, 0.f, 0.f};
#pragma unroll
  for (int hh = 0; hh < 2; ++hh) {
    const _Float16* wm = WTs + (size_t)(7 + hh) * 16384;
#pragma unroll
    for (int ks = 0; ks < 4; ++ks) {
      int ka = hh * 128 + ks * 32 + 4 * kg;
      half4v aa = *(const half4v*)&sV[mrow][ka];
      half4v ab = *(const half4v*)&sV[mrow][ka + 16];
      half8v af = __builtin_shufflevector(aa, ab, 0, 1, 2, 3, 4, 5, 6, 7);
      half8v bf0 = *(const half8v*)&wm[(size_t)(2 * wid) * 2048 + ks * 512 + lane * 8];
      half8v bf1 = *(const half8v*)&wm[(size_t)(2 * wid + 1) * 2048 + ks * 512 + lane * 8];
      m0 = __builtin_amdgcn_mfma_f32_16x16x32_f16(af, bf0, m0, 0, 0, 0);
      m1 = __builtin_amdgcn_mfma_f32_16x16x32_f16(af, bf1, m1, 0, 0, 0);
    }
  }
  float bm0 = b_mlp[colw + mrow];
  float bm1 = b_mlp[colw + 16 + mrow];
#pragma unroll
  for (int r = 0; r < 4; ++r) {
    out[(size_t)(node0 + 4 * kg + r) * 128 + colw + mrow] = m0[r] + bm0;
    out[(size_t)(node0 + 4 * kg + r) * 128 + colw + 16 + mrow] = m1[r] + bm1;
  }
}

extern "C" void kernel_launch(void* const* d_in, const int* in_sizes, int n_in,
                              void* d_out, int out_size, void* d_ws, size_t ws_size,
                              hipStream_t stream) {
  const float* x      = (const float*)d_in[0];
  const int* ei       = (const int*)d_in[1];
  const float* W_low  = (const float*)d_in[2];
  const float* b_low  = (const float*)d_in[3];
  const float* W_band = (const float*)d_in[4];
  const float* b_band = (const float*)d_in[5];
  const float* apre_l = (const float*)d_in[6];
  const float* ach_l  = (const float*)d_in[7];
  const float* apre_b = (const float*)d_in[8];
  const float* ach_b  = (const float*)d_in[9];
  const float* W_mlp  = (const float*)d_in[10];
  const float* b_mlp  = (const float*)d_in[11];
  float* out = (float*)d_out;

  char* ws = (char*)d_ws;
  size_t off = 0;
  auto take = [&](size_t bytes) -> void* {
    void* p = ws + off;
    off = (off + bytes + 255) & ~(size_t)255;
    return p;
  };
  int*   deg    = (int*)take((size_t)NN * 4);
  int*   fill   = (int*)take((size_t)NN * 4);
  size_t zero_bytes = off;  // deg + fill region
  float* dinv   = (float*)take((size_t)NN * 4);
  int*   rowptr = (int*)take((size_t)(NN + 1) * 4);
  int*   col    = (int*)take((size_t)NE * 4);
  float* wgt    = (float*)take((size_t)NE * 4);
  _Float16* xh  = (_Float16*)take((size_t)NN * 128 * 2);  // panel [4][NN][32]
  _Float16* a1h = (_Float16*)take((size_t)NN * 128 * 2);
  _Float16* a2h = (_Float16*)take((size_t)NN * 128 * 2);
  _Float16* a3h = (_Float16*)take((size_t)NN * 128 * 2);
  _Float16* a4h = (_Float16*)take((size_t)NN * 128 * 2);
  _Float16* WTs = (_Float16*)take((size_t)9 * 16384 * 2);
  (void)ws_size; (void)in_sizes; (void)n_in; (void)out_size;

  hipMemsetAsync(d_ws, 0, zero_bytes, stream);
  k_prep<<<9, 256, 0, stream>>>(W_low, W_band, W_mlp, WTs);
  k_x2p<<<(NN * 16 + 255) / 256, 256, 0, stream>>>(x, xh);
  k_deg<<<(NE + 255) / 256, 256, 0, stream>>>(ei, deg);
  k_dinv<<<(NN + 255) / 256, 256, 0, stream>>>(deg, dinv);
  k_scan<<<1, 1024, 0, stream>>>(deg, rowptr);
  k_fill<<<(NE + 255) / 256, 256, 0, stream>>>(ei, dinv, rowptr, fill, col, wgt);
  k_hop_p<<<4 * NB, 256, 0, stream>>>(xh,  a1h, rowptr, col, wgt);
  k_hop_p<<<4 * NB, 256, 0, stream>>>(a1h, a2h, rowptr, col, wgt);
  k_hop_p<<<4 * NB, 256, 0, stream>>>(a2h, a3h, rowptr, col, wgt);
  k_hop_p<<<4 * NB, 256, 0, stream>>>(a3h, a4h, rowptr, col, wgt);
  k_fused<<<NN / TM, 256, 0, stream>>>(xh, a1h, a2h, a4h, WTs, b_low, b_band,
                                       apre_l, ach_l, apre_b, ach_b, b_mlp, out);
}

// Round 10
// 425.949 us; speedup vs baseline: 1.0414x; 1.0414x over previous
//
#include <hip/hip_runtime.h>
#include <math.h>

#define NN 50000
#define NE 800000
#define TM 16

typedef _Float16 half4v __attribute__((ext_vector_type(4)));
typedef _Float16 half8v __attribute__((ext_vector_type(8)));
typedef float f32x4 __attribute__((ext_vector_type(4)));

__device__ __forceinline__ float relu(float v) { return fmaxf(v, 0.0f); }

// ---- degree count over dst ----
__global__ __launch_bounds__(256) void k_deg(const int* __restrict__ ei,
                                             int* __restrict__ deg) {
  int e = blockIdx.x * 256 + threadIdx.x;
  if (e < NE) atomicAdd(&deg[ei[NE + e]], 1);
}

// ---- d^-1/2 ----
__global__ __launch_bounds__(256) void k_dinv(const int* __restrict__ deg,
                                              float* __restrict__ dinv) {
  int i = blockIdx.x * 256 + threadIdx.x;
  if (i < NN) {
    int d = deg[i];
    dinv[i] = d > 0 ? 1.0f / sqrtf((float)d) : 0.0f;
  }
}

// ---- exclusive scan of deg -> rowptr (single 1024-thread block) ----
__global__ __launch_bounds__(1024) void k_scan(const int* __restrict__ deg,
                                               int* __restrict__ rowptr) {
  __shared__ int swave[16];
  __shared__ int scarry;
  const int tid = threadIdx.x;
  const int lane = tid & 63;
  const int wid = tid >> 6;
  if (tid == 0) scarry = 0;
  __syncthreads();
  for (int base = 0; base < NN; base += 1024) {
    int i = base + tid;
    int v = (i < NN) ? deg[i] : 0;
    int sum = v;
#pragma unroll
    for (int off = 1; off < 64; off <<= 1) {
      int t = __shfl_up(sum, off);
      if (lane >= off) sum += t;
    }
    if (lane == 63) swave[wid] = sum;
    __syncthreads();
    int wbase = 0;
    for (int w = 0; w < wid; ++w) wbase += swave[w];
    int carry = scarry;
    if (i < NN) rowptr[i] = carry + wbase + sum - v;
    __syncthreads();
    if (tid == 1023) scarry = carry + wbase + sum;
    __syncthreads();
  }
  if (tid == 0) rowptr[NN] = scarry;
}

// ---- CSR fill + edge weights ----
__global__ __launch_bounds__(256) void k_fill(const int* __restrict__ ei,
                                              const float* __restrict__ dinv,
                                              const int* __restrict__ rowptr,
                                              int* __restrict__ fill,
                                              int* __restrict__ col,
                                              float* __restrict__ wgt) {
  int e = blockIdx.x * 256 + threadIdx.x;
  if (e < NE) {
    int s = ei[e];
    int d = ei[NE + e];
    float w = dinv[s] * dinv[d] * 0.5f;
    int pos = rowptr[d] + atomicAdd(&fill[d], 1);
    col[pos] = s;
    wgt[pos] = w;
  }
}

// ---- x (f32 [N][128]) -> two half-tables f16 [2][N][64] ----
__global__ __launch_bounds__(256) void k_x2h(const float* __restrict__ x,
                                             _Float16* __restrict__ xh) {
  int i = blockIdx.x * 256 + threadIdx.x;  // NN*16 chunks of 8 floats
  if (i >= NN * 16) return;
  int n = i >> 4;
  int sub = i & 15;
  int half = sub >> 3, l = sub & 7;
  const float* src = x + (size_t)n * 128 + half * 64 + l * 8;
  float4 v0 = *(const float4*)src;
  float4 v1 = *(const float4*)(src + 4);
  half8v h;
  h[0] = (_Float16)v0.x; h[1] = (_Float16)v0.y;
  h[2] = (_Float16)v0.z; h[3] = (_Float16)v0.w;
  h[4] = (_Float16)v1.x; h[5] = (_Float16)v1.y;
  h[6] = (_Float16)v1.z; h[7] = (_Float16)v1.w;
  *(half8v*)(xh + (size_t)half * NN * 64 + (size_t)n * 64 + l * 8) = h;
}

// ---- one hop over one 64-col half-table (6.4 MB, full 128B-line rows) ----
// grid (ceil(NN*8/256), 2); 8 lanes/node x 16B; half = blockIdx.y
__global__ __launch_bounds__(256) void k_hop_h(const _Float16* __restrict__ in,
                                               _Float16* __restrict__ out,
                                               const int* __restrict__ rowptr,
                                               const int* __restrict__ col,
                                               const float* __restrict__ wgt) {
  int gidx = blockIdx.x * 256 + threadIdx.x;
  int node = gidx >> 3;
  int lane = gidx & 7;
  if (node >= NN) return;
  const size_t hoff = (size_t)blockIdx.y * NN * 64;
  const half8v* in8 = (const half8v*)(in + hoff);  // 8 x 16B per row
  half8v a = in8[(size_t)node * 8 + lane];
  float acc[8];
#pragma unroll
  for (int j = 0; j < 8; ++j) acc[j] = 0.5f * (float)a[j];
  int e = rowptr[node], e1 = rowptr[node + 1];
  for (; e + 4 <= e1; e += 4) {
    int c0 = __builtin_nontemporal_load(&col[e]);
    int c1 = __builtin_nontemporal_load(&col[e + 1]);
    int c2 = __builtin_nontemporal_load(&col[e + 2]);
    int c3 = __builtin_nontemporal_load(&col[e + 3]);
    float w0 = __builtin_nontemporal_load(&wgt[e]);
    float w1 = __builtin_nontemporal_load(&wgt[e + 1]);
    float w2 = __builtin_nontemporal_load(&wgt[e + 2]);
    float w3 = __builtin_nontemporal_load(&wgt[e + 3]);
    half8v v0 = in8[(size_t)c0 * 8 + lane];
    half8v v1 = in8[(size_t)c1 * 8 + lane];
    half8v v2 = in8[(size_t)c2 * 8 + lane];
    half8v v3 = in8[(size_t)c3 * 8 + lane];
#pragma unroll
    for (int j = 0; j < 8; ++j)
      acc[j] += w0 * (float)v0[j] + w1 * (float)v1[j] +
                w2 * (float)v2[j] + w3 * (float)v3[j];
  }
  for (; e < e1; ++e) {
    float w = __builtin_nontemporal_load(&wgt[e]);
    int c = __builtin_nontemporal_load(&col[e]);
    half8v v = in8[(size_t)c * 8 + lane];
#pragma unroll
    for (int j = 0; j < 8; ++j) acc[j] += w * (float)v[j];
  }
  half8v r;
#pragma unroll
  for (int j = 0; j < 8; ++j) r[j] = (_Float16)acc[j];
  __builtin_nontemporal_store(r, (half8v*)(out + hoff) + (size_t)node * 8 + lane);
}

// ---- prep: weights -> f16 fragment-order [m][ct(8)][ks(4)][lane(64)][8] ----
__global__ __launch_bounds__(256) void k_prep(const float* __restrict__ W_low,
                                              const float* __restrict__ W_band,
                                              const float* __restrict__ W_mlp,
                                              _Float16* __restrict__ WTs) {
  int m = blockIdx.x;  // 0..6 channels, 7..8 mlp chunks
  const float* src;
  if (m < 4)      src = W_low + m * 16384;
  else if (m < 7) src = W_band + (m - 4) * 16384;
  else            src = W_mlp + (m - 7) * 16384;
  _Float16* dst = WTs + (size_t)m * 16384;
  for (int s = threadIdx.x; s < 2048; s += 256) {
    int ct = s >> 8;          // col tile 0..7
    int ks = (s >> 6) & 3;    // k step 0..3
    int lane = s & 63;
    int mcol = lane & 15, kg = lane >> 4;
    int colc = ct * 16 + mcol;
    int k0 = ks * 32 + 4 * kg;
    _Float16* d = dst + (size_t)s * 8;
#pragma unroll
    for (int j = 0; j < 4; ++j) d[j] = (_Float16)src[(k0 + j) * 128 + colc];
#pragma unroll
    for (int j = 0; j < 4; ++j) d[4 + j] = (_Float16)src[(k0 + 16 + j) * 128 + colc];
  }
}

// A-fragment load from half-table layout: ks 0,1 -> half 0; ks 2,3 -> half 1
#define LOADH(dst, src)                                                        \
  {                                                                            \
    _Pragma("unroll")                                                          \
    for (int ks = 0; ks < 4; ++ks) {                                           \
      const _Float16* p_ = (src) + (size_t)(ks >> 1) * NN * 64 +               \
                           (size_t)(node0 + mrow) * 64 + (ks & 1) * 32;        \
      half4v lo_ = *(const half4v*)&p_[4 * kg];                                \
      half4v hi_ = *(const half4v*)&p_[4 * kg + 16];                           \
      dst[ks] = __builtin_shufflevector(lo_, hi_, 0, 1, 2, 3, 4, 5, 6, 7);     \
    }                                                                          \
  }

// One channel GEMM: f32 accumulate, bias added, packed to f16 registers
#define CH_GEMM(c, AEXPR, BIASPTR)                                             \
  {                                                                            \
    const _Float16* wc_ = WTs + (size_t)(c) * 16384;                           \
    f32x4 A0_ = {0.f, 0.f, 0.f, 0.f}, A1_ = {0.f, 0.f, 0.f, 0.f};              \
    _Pragma("unroll")                                                          \
    for (int ks = 0; ks < 4; ++ks) {                                           \
      half8v af_ = (AEXPR);                                                    \
      half8v bf0_ = *(const half8v*)&wc_[(size_t)(2 * wid) * 2048 + ks * 512 + lane * 8];     \
      half8v bf1_ = *(const half8v*)&wc_[(size_t)(2 * wid + 1) * 2048 + ks * 512 + lane * 8]; \
      A0_ = __builtin_amdgcn_mfma_f32_16x16x32_f16(af_, bf0_, A0_, 0, 0, 0);   \
      A1_ = __builtin_amdgcn_mfma_f32_16x16x32_f16(af_, bf1_, A1_, 0, 0, 0);   \
    }                                                                          \
    float bv0_ = (BIASPTR)[colw + mrow], bv1_ = (BIASPTR)[colw + 16 + mrow];   \
    half4v H0_, H1_;                                                           \
    _Pragma("unroll")                                                          \
    for (int r = 0; r < 4; ++r) {                                              \
      H0_[r] = (_Float16)(A0_[r] + bv0_);                                      \
      H1_[r] = (_Float16)(A1_[r] + bv1_);                                      \
    }                                                                          \
    h0[c] = H0_; h1[c] = H1_;                                                  \
  }

// ---- fused MFMA: 7-channel GEMM (h in f16 registers) + attention + MLP ----
__global__ __launch_bounds__(256) void k_fused(
    const _Float16* __restrict__ xh, const _Float16* __restrict__ a1,
    const _Float16* __restrict__ a2, const _Float16* __restrict__ a4,
    const _Float16* __restrict__ WTs,
    const float* __restrict__ b_low, const float* __restrict__ b_band,
    const float* __restrict__ apre_l, const float* __restrict__ ach_l,
    const float* __restrict__ apre_b, const float* __restrict__ ach_b,
    const float* __restrict__ b_mlp, float* __restrict__ out) {
  __shared__ float pD[2][TM][4];     // [low|band][node][wave] pre-dot partials
  __shared__ float pS[7][TM][4];     // [chan][node][wave] chan-dot partials
  __shared__ float aB[TM][8];        // alpha per node (7 used)
  __shared__ _Float16 sV[TM][264];   // MLP input [node][256]+pad

  const int tid = threadIdx.x;
  const int wid = tid >> 6;
  const int lane = tid & 63;
  const int mrow = lane & 15;
  const int kg = lane >> 4;
  const int node0 = blockIdx.x * TM;
  const int colw = wid * 32;

  half4v h0[7], h1[7];  // per-channel outputs (bias included), f16-packed

  // ---- all 32 A-fragment loads issued upfront (one latency exposure) ----
  half8v fX[4], f1[4], f2[4], f4[4];
  LOADH(fX, xh);
  LOADH(f1, a1);
  LOADH(f2, a2);
  LOADH(f4, a4);

  CH_GEMM(0, fX[ks], b_low + 0 * 128);
  CH_GEMM(4, fX[ks] - f1[ks], b_band + 0 * 128);
  CH_GEMM(1, f1[ks], b_low + 1 * 128);
  CH_GEMM(5, f1[ks] - f2[ks], b_band + 1 * 128);
  CH_GEMM(2, f2[ks], b_low + 2 * 128);
  CH_GEMM(6, f2[ks] - f4[ks], b_band + 2 * 128);
  CH_GEMM(3, f4[ks], b_low + 3 * 128);

  // ---- attention partials in-register ----
  const float apl0 = apre_l[colw + mrow], apl1 = apre_l[colw + 16 + mrow];
  const float acl0 = ach_l[colw + mrow],  acl1 = ach_l[colw + 16 + mrow];
  const float apb0 = apre_b[colw + mrow], apb1 = apre_b[colw + 16 + mrow];
  const float acb0 = ach_b[colw + mrow],  acb1 = ach_b[colw + 16 + mrow];

  float dpl[4] = {0.f, 0.f, 0.f, 0.f}, dpb[4] = {0.f, 0.f, 0.f, 0.f};
  float sc[7][4];
#pragma unroll
  for (int c = 0; c < 7; ++c) {
#pragma unroll
    for (int r = 0; r < 4; ++r) {
      float r0 = relu((float)h0[c][r]);
      float r1 = relu((float)h1[c][r]);
      if (c < 4) {
        dpl[r] += r0 * apl0 + r1 * apl1;
        sc[c][r] = r0 * acl0 + r1 * acl1;
      } else {
        dpb[r] += r0 * apb0 + r1 * apb1;
        sc[c][r] = r0 * acb0 + r1 * acb1;
      }
    }
  }
#pragma unroll
  for (int r = 0; r < 4; ++r) { dpl[r] *= 0.25f; dpb[r] *= (1.0f / 3.0f); }
  // reduce over the 16 mrow lanes (lane bits 0..3)
#pragma unroll
  for (int m = 1; m <= 8; m <<= 1) {
#pragma unroll
    for (int r = 0; r < 4; ++r) {
      dpl[r] += __shfl_xor(dpl[r], m);
      dpb[r] += __shfl_xor(dpb[r], m);
    }
#pragma unroll
    for (int c = 0; c < 7; ++c)
#pragma unroll
      for (int r = 0; r < 4; ++r) sc[c][r] += __shfl_xor(sc[c][r], m);
  }
  if (mrow == 0) {
#pragma unroll
    for (int r = 0; r < 4; ++r) {
      pD[0][4 * kg + r][wid] = dpl[r];
      pD[1][4 * kg + r][wid] = dpb[r];
#pragma unroll
      for (int c = 0; c < 7; ++c) pS[c][4 * kg + r][wid] = sc[c][r];
    }
  }
  __syncthreads();

  // ---- softmax over channels (one thread per node) ----
  if (tid < TM) {
    const int n = tid;
    float dl = pD[0][n][0] + pD[0][n][1] + pD[0][n][2] + pD[0][n][3];
    float db = pD[1][n][0] + pD[1][n][1] + pD[1][n][2] + pD[1][n][3];
    float lg[7];
#pragma unroll
    for (int c = 0; c < 7; ++c) {
      float s = pS[c][n][0] + pS[c][n][1] + pS[c][n][2] + pS[c][n][3];
      lg[c] = relu((c < 4 ? dl : db) + s);
    }
    float ml = fmaxf(fmaxf(lg[0], lg[1]), fmaxf(lg[2], lg[3]));
    float e0 = expf(lg[0] - ml), e1 = expf(lg[1] - ml);
    float e2 = expf(lg[2] - ml), e3 = expf(lg[3] - ml);
    float invl = 1.0f / (e0 + e1 + e2 + e3);
    float mb = fmaxf(fmaxf(lg[4], lg[5]), lg[6]);
    float f4e = expf(lg[4] - mb), f5e = expf(lg[5] - mb), f6e = expf(lg[6] - mb);
    float invb = 1.0f / (f4e + f5e + f6e);
    aB[n][0] = e0 * invl; aB[n][1] = e1 * invl;
    aB[n][2] = e2 * invl; aB[n][3] = e3 * invl;
    aB[n][4] = f4e * invb; aB[n][5] = f5e * invb; aB[n][6] = f6e * invb;
  }
  __syncthreads();

  // ---- weighted sum straight from registers -> sV ----
#pragma unroll
  for (int r = 0; r < 4; ++r) {
    const int n = 4 * kg + r;
    float vl0 = 0.f, vl1 = 0.f, vb0 = 0.f, vb1 = 0.f;
#pragma unroll
    for (int c = 0; c < 4; ++c) {
      float a = aB[n][c];
      vl0 += a * (float)h0[c][r];
      vl1 += a * (float)h1[c][r];
    }
#pragma unroll
    for (int c = 4; c < 7; ++c) {
      float a = aB[n][c];
      vb0 += a * (float)h0[c][r];
      vb1 += a * (float)h1[c][r];
    }
    sV[n][colw + mrow] = (_Float16)vl0;
    sV[n][colw + 16 + mrow] = (_Float16)vl1;
    sV[n][128 + colw + mrow] = (_Float16)vb0;
    sV[n][128 + colw + 16 + mrow] = (_Float16)vb1;
  }
  __syncthreads();

  // ---- MLP: [TM,256] @ [256,128], coalesced B frags ----
  f32x4 m0 = {0.f, 0.f, 0.f, 0.f}, m1 = {0.f, 0.f, 0.f, 0.f};
#pragma unroll
  for (int hh = 0; hh < 2; ++hh) {
    const _Float16* wm = WTs + (size_t)(7 + hh) * 16384;
#pragma unroll
    for (int ks = 0; ks < 4; ++ks) {
      int ka = hh * 128 + ks * 32 + 4 * kg;
      half4v aa = *(const half4v*)&sV[mrow][ka];
      half4v ab = *(const half4v*)&sV[mrow][ka + 16];
      half8v af = __builtin_shufflevector(aa, ab, 0, 1, 2, 3, 4, 5, 6, 7);
      half8v bf0 = *(const half8v*)&wm[(size_t)(2 * wid) * 2048 + ks * 512 + lane * 8];
      half8v bf1 = *(const half8v*)&wm[(size_t)(2 * wid + 1) * 2048 + ks * 512 + lane * 8];
      m0 = __builtin_amdgcn_mfma_f32_16x16x32_f16(af, bf0, m0, 0, 0, 0);
      m1 = __builtin_amdgcn_mfma_f32_16x16x32_f16(af, bf1, m1, 0, 0, 0);
    }
  }
  float bm0 = b_mlp[colw + mrow];
  float bm1 = b_mlp[colw + 16 + mrow];
#pragma unroll
  for (int r = 0; r < 4; ++r) {
    out[(size_t)(node0 + 4 * kg + r) * 128 + colw + mrow] = m0[r] + bm0;
    out[(size_t)(node0 + 4 * kg + r) * 128 + colw + 16 + mrow] = m1[r] + bm1;
  }
}

extern "C" void kernel_launch(void* const* d_in, const int* in_sizes, int n_in,
                              void* d_out, int out_size, void* d_ws, size_t ws_size,
                              hipStream_t stream) {
  const float* x      = (const float*)d_in[0];
  const int* ei       = (const int*)d_in[1];
  const float* W_low  = (const float*)d_in[2];
  const float* b_low  = (const float*)d_in[3];
  const float* W_band = (const float*)d_in[4];
  const float* b_band = (const float*)d_in[5];
  const float* apre_l = (const float*)d_in[6];
  const float* ach_l  = (const float*)d_in[7];
  const float* apre_b = (const float*)d_in[8];
  const float* ach_b  = (const float*)d_in[9];
  const float* W_mlp  = (const float*)d_in[10];
  const float* b_mlp  = (const float*)d_in[11];
  float* out = (float*)d_out;

  char* ws = (char*)d_ws;
  size_t off = 0;
  auto take = [&](size_t bytes) -> void* {
    void* p = ws + off;
    off = (off + bytes + 255) & ~(size_t)255;
    return p;
  };
  int*   deg    = (int*)take((size_t)NN * 4);
  int*   fill   = (int*)take((size_t)NN * 4);
  size_t zero_bytes = off;  // deg + fill region
  float* dinv   = (float*)take((size_t)NN * 4);
  int*   rowptr = (int*)take((size_t)(NN + 1) * 4);
  int*   col    = (int*)take((size_t)NE * 4);
  float* wgt    = (float*)take((size_t)NE * 4);
  _Float16* xh  = (_Float16*)take((size_t)NN * 128 * 2);  // [2][NN][64]
  _Float16* a1h = (_Float16*)take((size_t)NN * 128 * 2);
  _Float16* a2h = (_Float16*)take((size_t)NN * 128 * 2);
  _Float16* a3h = (_Float16*)take((size_t)NN * 128 * 2);
  _Float16* a4h = (_Float16*)take((size_t)NN * 128 * 2);
  _Float16* WTs = (_Float16*)take((size_t)9 * 16384 * 2);
  (void)ws_size; (void)in_sizes; (void)n_in; (void)out_size;

  hipMemsetAsync(d_ws, 0, zero_bytes, stream);
  k_prep<<<9, 256, 0, stream>>>(W_low, W_band, W_mlp, WTs);
  k_x2h<<<(NN * 16 + 255) / 256, 256, 0, stream>>>(x, xh);
  k_deg<<<(NE + 255) / 256, 256, 0, stream>>>(ei, deg);
  k_dinv<<<(NN + 255) / 256, 256, 0, stream>>>(deg, dinv);
  k_scan<<<1, 1024, 0, stream>>>(deg, rowptr);
  k_fill<<<(NE + 255) / 256, 256, 0, stream>>>(ei, dinv, rowptr, fill, col, wgt);
  dim3 hgrid((NN * 8 + 255) / 256, 2);
  k_hop_h<<<hgrid, 256, 0, stream>>>(xh,  a1h, rowptr, col, wgt);
  k_hop_h<<<hgrid, 256, 0, stream>>>(a1h, a2h, rowptr, col, wgt);
  k_hop_h<<<hgrid, 256, 0, stream>>>(a2h, a3h, rowptr, col, wgt);
  k_hop_h<<<hgrid, 256, 0, stream>>>(a3h, a4h, rowptr, col, wgt);
  k_fused<<<NN / TM, 256, 0, stream>>>(xh, a1h, a2h, a4h, WTs, b_low, b_band,
                                       apre_l, ach_l, apre_b, ach_b, b_mlp, out);
}